// Round 1
// baseline (355.243 us; speedup 1.0000x reference)
//
#include <hip/hip_runtime.h>

#define B 256
#define S 24
#define D 256
#define N 8192
#define EPSF 1e-8f

// One block per output row (b, i). 256 threads.
// patch_attn accumulator lives in registers: 8 x float4 = 32 floats/thread
// (256 threads * 32 = 8192 = N). Each input row is read by exactly one block
// (its cluster), so patch_attn is read once and written once: ~402 MB total
// HBM traffic -> memory-bound, floor ~67 us at 6.3 TB/s.
__global__ __launch_bounds__(256) void slot_merge_kernel(
    const float* __restrict__ slots,     // [B,S,D]
    const float* __restrict__ patch,     // [B,S,N]
    const int*   __restrict__ clusters,  // [B,S]
    float* __restrict__ out_slots,       // [B,S,D]
    float* __restrict__ out_patch,       // [B,S,N]
    float* __restrict__ out_nums)        // [B] (written as float)
{
    const int blk = blockIdx.x;
    const int b   = blk / S;
    const int i   = blk % S;   // cluster id this block produces
    const int tid = threadIdx.x;

    __shared__ int cl[S];
    if (tid < S) cl[tid] = clusters[b * S + tid];
    __syncthreads();

    // ---- patch_attn: acc[n] = sum_{j: cl[j]==i} patch[b,j,n] + EPS ----
    float4 acc[8];
    #pragma unroll
    for (int k = 0; k < 8; ++k) acc[k] = make_float4(EPSF, EPSF, EPSF, EPSF);

    int m = 0;  // member count of this cluster
    for (int j = 0; j < S; ++j) {
        if (cl[j] != i) continue;   // wave-uniform branch: cl[j], i uniform per block
        ++m;
        const float4* __restrict__ row =
            (const float4*)(patch + ((size_t)b * S + j) * N);
        #pragma unroll
        for (int k = 0; k < 8; ++k) {
            float4 v = row[tid + k * 256];   // coalesced: 64 lanes x 16B contiguous
            acc[k].x += v.x; acc[k].y += v.y; acc[k].z += v.z; acc[k].w += v.w;
        }
    }

    // ---- row total = sum_n acc[n] (includes the +EPS per element) ----
    float lsum = 0.f;
    #pragma unroll
    for (int k = 0; k < 8; ++k) lsum += acc[k].x + acc[k].y + acc[k].z + acc[k].w;

    // wave (64-lane) reduction then cross-wave via LDS
    #pragma unroll
    for (int off = 32; off > 0; off >>= 1) lsum += __shfl_down(lsum, off, 64);
    __shared__ float wsum[4];
    if ((tid & 63) == 0) wsum[tid >> 6] = lsum;
    __syncthreads();
    const float total = wsum[0] + wsum[1] + wsum[2] + wsum[3];
    const float inv = 1.0f / total;

    float4* __restrict__ orow = (float4*)(out_patch + ((size_t)b * S + i) * N);
    #pragma unroll
    for (int k = 0; k < 8; ++k) {
        float4 v = acc[k];
        v.x *= inv; v.y *= inv; v.z *= inv; v.w *= inv;
        orow[tid + k * 256] = v;
    }

    // ---- slots: one element of D per thread ----
    float sacc = 0.f;
    for (int j = 0; j < S; ++j) {
        if (cl[j] != i) continue;
        sacc += slots[((size_t)b * S + j) * D + tid];
    }
    out_slots[((size_t)b * S + i) * D + tid] = sacc / ((float)m + EPSF);

    // ---- slot_nums[b]: number of distinct clusters present ----
    if (i == 0 && tid == 0) {
        int cnt = 0;
        for (int c = 0; c < S; ++c) {
            bool found = false;
            for (int j = 0; j < S; ++j) {
                if (cl[j] == c) { found = true; break; }
            }
            cnt += found ? 1 : 0;
        }
        out_nums[b] = (float)cnt;
    }
}

extern "C" void kernel_launch(void* const* d_in, const int* in_sizes, int n_in,
                              void* d_out, int out_size, void* d_ws, size_t ws_size,
                              hipStream_t stream) {
    const float* slots    = (const float*)d_in[0];
    const float* patch    = (const float*)d_in[1];
    const int*   clusters = (const int*)d_in[2];

    float* out       = (float*)d_out;
    float* out_slots = out;                                   // B*S*D
    float* out_patch = out + (size_t)B * S * D;               // B*S*N
    float* out_nums  = out + (size_t)B * S * D + (size_t)B * S * N;  // B

    slot_merge_kernel<<<B * S, 256, 0, stream>>>(
        slots, patch, clusters, out_slots, out_patch, out_nums);
}

// Round 3
// 343.280 us; speedup vs baseline: 1.0348x; 1.0348x over previous
//
#include <hip/hip_runtime.h>

#define B 256
#define S 24
#define D 256
#define N 8192
#define EPSF 1e-8f

// clang-native 16B vector type: __builtin_nontemporal_* accepts vectors of
// float, but NOT HIP's struct-based float4.
typedef float vfloat4 __attribute__((ext_vector_type(4)));

// One block per output row (b, i). 256 threads, 32 floats/thread of the
// N=8192 accumulator held in registers (8 x vfloat4).
//
// Traffic is algorithmically minimal: every patch row is read by exactly one
// block (its cluster's block) and every output row written once ->
// ~415 MB total -> ~66 us floor at 6.3 TB/s. Zero data reuse, so all big
// streams use non-temporal (nt) loads/stores to bypass L2 allocation.
// Member rows are consumed two at a time (16 x 16B loads in flight) to
// deepen MLP before the accumulate waitcnt.
__global__ __launch_bounds__(256) void slot_merge_kernel(
    const float* __restrict__ slots,     // [B,S,D]
    const float* __restrict__ patch,     // [B,S,N]
    const int*   __restrict__ clusters,  // [B,S]
    float* __restrict__ out_slots,       // [B,S,D]
    float* __restrict__ out_patch,       // [B,S,N]
    float* __restrict__ out_nums)        // [B] (written as float)
{
    const int blk = blockIdx.x;
    const int b   = blk / S;
    const int i   = blk % S;   // cluster id this block produces
    const int tid = threadIdx.x;

    __shared__ int cl[S];
    if (tid < S) cl[tid] = clusters[b * S + tid];
    __syncthreads();

    // membership bitmask (uniform across the block)
    unsigned mask = 0u;
    #pragma unroll
    for (int j = 0; j < S; ++j) mask |= (cl[j] == i ? 1u : 0u) << j;
    const int m = __popc(mask);

    vfloat4 acc[8];
    #pragma unroll
    for (int k = 0; k < 8; ++k) acc[k] = (vfloat4)(EPSF);

    const vfloat4* __restrict__ base = (const vfloat4*)(patch + (size_t)b * S * N);

    unsigned rem = mask;
    // two member rows per iteration: 16 x 16B loads in flight per thread
    while (__popc(rem) >= 2) {
        const int j0 = __builtin_ctz(rem); rem &= rem - 1u;
        const int j1 = __builtin_ctz(rem); rem &= rem - 1u;
        const vfloat4* __restrict__ r0 = base + (size_t)j0 * (N / 4);
        const vfloat4* __restrict__ r1 = base + (size_t)j1 * (N / 4);
        vfloat4 v0[8], v1[8];
        #pragma unroll
        for (int k = 0; k < 8; ++k) v0[k] = __builtin_nontemporal_load(&r0[tid + k * 256]);
        #pragma unroll
        for (int k = 0; k < 8; ++k) v1[k] = __builtin_nontemporal_load(&r1[tid + k * 256]);
        #pragma unroll
        for (int k = 0; k < 8; ++k) acc[k] += v0[k] + v1[k];
    }
    if (rem) {  // odd leftover row
        const int j0 = __builtin_ctz(rem);
        const vfloat4* __restrict__ r0 = base + (size_t)j0 * (N / 4);
        vfloat4 v0[8];
        #pragma unroll
        for (int k = 0; k < 8; ++k) v0[k] = __builtin_nontemporal_load(&r0[tid + k * 256]);
        #pragma unroll
        for (int k = 0; k < 8; ++k) acc[k] += v0[k];
    }

    // ---- row total = sum_n acc[n] (each element already includes +EPS) ----
    float lsum = 0.f;
    #pragma unroll
    for (int k = 0; k < 8; ++k) lsum += acc[k].x + acc[k].y + acc[k].z + acc[k].w;

    #pragma unroll
    for (int off = 32; off > 0; off >>= 1) lsum += __shfl_down(lsum, off, 64);
    __shared__ float wsum[4];
    if ((tid & 63) == 0) wsum[tid >> 6] = lsum;
    __syncthreads();
    const float total = wsum[0] + wsum[1] + wsum[2] + wsum[3];
    const float inv = 1.0f / total;

    vfloat4* __restrict__ orow = (vfloat4*)(out_patch + ((size_t)b * S + i) * N);
    #pragma unroll
    for (int k = 0; k < 8; ++k) {
        vfloat4 v = acc[k] * inv;
        __builtin_nontemporal_store(v, &orow[tid + k * 256]);
    }

    // ---- slots: one element of D per thread (small: 6 MB each way) ----
    float sacc = 0.f;
    unsigned rem2 = mask;
    while (rem2) {
        const int j = __builtin_ctz(rem2); rem2 &= rem2 - 1u;
        sacc += slots[((size_t)b * S + j) * D + tid];
    }
    out_slots[((size_t)b * S + i) * D + tid] = sacc / ((float)m + EPSF);

    // ---- slot_nums[b]: number of distinct clusters present ----
    if (i == 0 && tid == 0) {
        unsigned present = 0u;
        #pragma unroll
        for (int j = 0; j < S; ++j) present |= 1u << cl[j];
        out_nums[b] = (float)__popc(present);
    }
}

extern "C" void kernel_launch(void* const* d_in, const int* in_sizes, int n_in,
                              void* d_out, int out_size, void* d_ws, size_t ws_size,
                              hipStream_t stream) {
    const float* slots    = (const float*)d_in[0];
    const float* patch    = (const float*)d_in[1];
    const int*   clusters = (const int*)d_in[2];

    float* out       = (float*)d_out;
    float* out_slots = out;                                          // B*S*D
    float* out_patch = out + (size_t)B * S * D;                      // B*S*N
    float* out_nums  = out + (size_t)B * S * D + (size_t)B * S * N;  // B

    slot_merge_kernel<<<B * S, 256, 0, stream>>>(
        slots, patch, clusters, out_slots, out_patch, out_nums);
}

// Round 4
// 340.479 us; speedup vs baseline: 1.0434x; 1.0082x over previous
//
#include <hip/hip_runtime.h>

#define B 256
#define S 24
#define D 256
#define N 8192
#define EPSF 1e-8f

// clang-native 16B vector type (__builtin_nontemporal_* rejects HIP's
// struct-based float4).
typedef float vfloat4 __attribute__((ext_vector_type(4)));

// One block per output row (b, i). 512 threads x 16 floats/thread = N=8192.
// vs R3 (256 thr x 32 floats): same in-flight load bytes (VGPR-bound), but
// ~2x resident waves/CU -> better coverage of each block's reduce/store
// phase by other blocks' read bursts.
//
// Traffic is algorithmically minimal (~415 MB -> ~66 us floor at 6.3 TB/s):
// every patch row read exactly once, every output row written once. Zero
// reuse -> nt loads/stores bypass L2 allocation.
__global__ __launch_bounds__(512) void slot_merge_kernel(
    const float* __restrict__ slots,     // [B,S,D]
    const float* __restrict__ patch,     // [B,S,N]
    const int*   __restrict__ clusters,  // [B,S]
    float* __restrict__ out_slots,       // [B,S,D]
    float* __restrict__ out_patch,       // [B,S,N]
    float* __restrict__ out_nums)        // [B] (written as float)
{
    const int blk = blockIdx.x;
    const int b   = blk / S;
    const int i   = blk % S;   // cluster id this block produces
    const int tid = threadIdx.x;

    __shared__ int cl[S];
    if (tid < S) cl[tid] = clusters[b * S + tid];
    __syncthreads();

    // membership bitmask — block-uniform; force into an SGPR so row
    // addressing scalarizes (global_load with SGPR base + voffset).
    unsigned mask = 0u;
    #pragma unroll
    for (int j = 0; j < S; ++j) mask |= (cl[j] == i ? 1u : 0u) << j;
    mask = __builtin_amdgcn_readfirstlane(mask);
    const int m = __popc(mask);

    // ---- slots accumulation issued FIRST so its loads overlap the patch
    //      read burst instead of sitting latency-exposed at the kernel tail.
    //      Threads 0..255 each own one d; waves 4..7 skip (wave-granular). ----
    float sacc = 0.f;
    if (tid < D) {
        unsigned rem2 = mask;
        while (rem2) {
            const int j = __builtin_ctz(rem2); rem2 &= rem2 - 1u;
            sacc += slots[((size_t)b * S + j) * D + tid];
        }
    }

    // ---- patch_attn: acc[n] = EPS + sum_{j: cl[j]==i} patch[b,j,n] ----
    vfloat4 acc[4];
    #pragma unroll
    for (int k = 0; k < 4; ++k) acc[k] = (vfloat4)(EPSF);

    const vfloat4* __restrict__ base = (const vfloat4*)(patch + (size_t)b * S * N);

    unsigned rem = mask;
    while (__popc(rem) >= 2) {   // two member rows per iteration
        const int j0 = __builtin_ctz(rem); rem &= rem - 1u;
        const int j1 = __builtin_ctz(rem); rem &= rem - 1u;
        const vfloat4* __restrict__ r0 = base + (size_t)j0 * (N / 4);
        const vfloat4* __restrict__ r1 = base + (size_t)j1 * (N / 4);
        vfloat4 v0[4], v1[4];
        #pragma unroll
        for (int k = 0; k < 4; ++k) v0[k] = __builtin_nontemporal_load(&r0[tid + k * 512]);
        #pragma unroll
        for (int k = 0; k < 4; ++k) v1[k] = __builtin_nontemporal_load(&r1[tid + k * 512]);
        #pragma unroll
        for (int k = 0; k < 4; ++k) acc[k] += v0[k] + v1[k];
    }
    if (rem) {  // odd leftover row
        const int j0 = __builtin_ctz(rem);
        const vfloat4* __restrict__ r0 = base + (size_t)j0 * (N / 4);
        vfloat4 v0[4];
        #pragma unroll
        for (int k = 0; k < 4; ++k) v0[k] = __builtin_nontemporal_load(&r0[tid + k * 512]);
        #pragma unroll
        for (int k = 0; k < 4; ++k) acc[k] += v0[k];
    }

    // ---- row total = sum_n acc[n] (each element already includes +EPS) ----
    float lsum = 0.f;
    #pragma unroll
    for (int k = 0; k < 4; ++k) lsum += acc[k].x + acc[k].y + acc[k].z + acc[k].w;

    #pragma unroll
    for (int off = 32; off > 0; off >>= 1) lsum += __shfl_down(lsum, off, 64);
    __shared__ float wsum[8];
    if ((tid & 63) == 0) wsum[tid >> 6] = lsum;
    __syncthreads();
    float total = 0.f;
    #pragma unroll
    for (int w = 0; w < 8; ++w) total += wsum[w];
    const float inv = 1.0f / total;

    vfloat4* __restrict__ orow = (vfloat4*)(out_patch + ((size_t)b * S + i) * N);
    #pragma unroll
    for (int k = 0; k < 4; ++k) {
        vfloat4 v = acc[k] * inv;
        __builtin_nontemporal_store(v, &orow[tid + k * 512]);
    }

    // ---- slots epilogue: mean over members ----
    if (tid < D) {
        out_slots[((size_t)b * S + i) * D + tid] = sacc / ((float)m + EPSF);
    }

    // ---- slot_nums[b]: number of distinct clusters present ----
    if (i == 0 && tid == 0) {
        unsigned present = 0u;
        #pragma unroll
        for (int j = 0; j < S; ++j) present |= 1u << cl[j];
        out_nums[b] = (float)__popc(present);
    }
}

extern "C" void kernel_launch(void* const* d_in, const int* in_sizes, int n_in,
                              void* d_out, int out_size, void* d_ws, size_t ws_size,
                              hipStream_t stream) {
    const float* slots    = (const float*)d_in[0];
    const float* patch    = (const float*)d_in[1];
    const int*   clusters = (const int*)d_in[2];

    float* out       = (float*)d_out;
    float* out_slots = out;                                          // B*S*D
    float* out_patch = out + (size_t)B * S * D;                      // B*S*N
    float* out_nums  = out + (size_t)B * S * D + (size_t)B * S * N;  // B

    slot_merge_kernel<<<B * S, 512, 0, stream>>>(
        slots, patch, clusters, out_slots, out_patch, out_nums);
}